// Round 1
// 712.146 us; speedup vs baseline: 1.0664x; 1.0664x over previous
//
#include <hip/hip_runtime.h>
#include <hip/hip_bf16.h>
#include <cstddef>

// GCN: h0 = relu(spmm(x@W0^T)); h1 = relu(spmm(h0@W1^T)); out = spmm(h1@W2^T)
// R7: direct 2-pass CSR build (hist -> scan -> scatter straight into
// row-contiguous es2; cur seeded from the scan's mirror output) replaces the
// 8-slice build + reorder: 12 build launches -> 6, ~50 MB less intermediate
// traffic. SpMM regrouped to 16 lanes x 16B per edge, 4 groups x 4 unroll =
// 16 edges in flight per wave (was 8) to hide L2/L3 gather latency.

typedef unsigned short ushort_t;
using frag_t = __attribute__((ext_vector_type(8))) short;   // 8 bf16
using accf4 = __attribute__((ext_vector_type(4))) float;    // 4 fp32

__device__ __forceinline__ ushort_t f2bf(float f) {
    unsigned int u = __float_as_uint(f);
    u += 0x7FFF + ((u >> 16) & 1);   // RNE
    return (ushort_t)(u >> 16);
}
__device__ __forceinline__ float bf2f(unsigned int u16) {
    return __uint_as_float(u16 << 16);
}

// ---------------- init: zero row counters + convert all weights ----------------

__global__ __launch_bounds__(256) void init_k(int* __restrict__ cnt, int n,
                                              const float* __restrict__ W0,
                                              const float* __restrict__ W1,
                                              const float* __restrict__ W2,
                                              ushort_t* __restrict__ Wb0,
                                              ushort_t* __restrict__ Wb1,
                                              ushort_t* __restrict__ Wb2) {
    int i = blockIdx.x * 256 + threadIdx.x;
    if (i < n) cnt[i] = 0;
    if (i < 65536) Wb0[i] = f2bf(W0[i]);
    else if (i < 81920) Wb1[i - 65536] = f2bf(W1[i - 65536]);
    else if (i < 90112) Wb2[i - 81920] = f2bf(W2[i - 81920]);
}

// ---------------- scan building blocks ----------------

__global__ __launch_bounds__(256) void block_totals(const int* __restrict__ counts,
                                                    int* __restrict__ bsums, int n) {
    __shared__ int s[256];
    int t = threadIdx.x;
    int i = blockIdx.x * 256 + t;
    s[t] = (i < n) ? counts[i] : 0;
    __syncthreads();
    for (int off = 128; off > 0; off >>= 1) {
        if (t < off) s[t] += s[t + off];
        __syncthreads();
    }
    if (t == 0) bsums[blockIdx.x] = s[0];
}

// single block, 512 threads: exclusive scan of nb (<=512) values in place
__global__ __launch_bounds__(512) void scan_sums(int* bsums, int nb) {
    __shared__ int s[512];
    int t = threadIdx.x;
    int v = (t < nb) ? bsums[t] : 0;
    s[t] = v;
    __syncthreads();
    for (int off = 1; off < 512; off *= 2) {
        int u = (t >= off) ? s[t - off] : 0;
        __syncthreads();
        s[t] += u;
        __syncthreads();
    }
    if (t < nb) bsums[t] = s[t] - v;  // exclusive
}

// exclusive scan with per-block offsets; mirrors to out1 (cur seed) and writes
// the array total at *tail.
__global__ __launch_bounds__(256) void scan_wo(const int* __restrict__ data,
                                               const int* __restrict__ offs,
                                               int* __restrict__ out0,
                                               int* __restrict__ out1,
                                               int* __restrict__ tail, int tailval,
                                               int m) {
    __shared__ int s[256];
    int t = threadIdx.x;
    int i = blockIdx.x * 256 + t;
    int v = (i < m) ? data[i] : 0;
    s[t] = v;
    __syncthreads();
    for (int off = 1; off < 256; off *= 2) {
        int u = (t >= off) ? s[t - off] : 0;
        __syncthreads();
        s[t] += u;
        __syncthreads();
    }
    int excl = s[t] - v + offs[blockIdx.x];
    if (i < m) {
        out0[i] = excl;
        if (out1) out1[i] = excl;
    }
    if (i == 0 && tail) *tail = tailval;
}

// ---------------- direct CSR build ----------------

__global__ __launch_bounds__(256) void hist_k(const int* __restrict__ rows,
                                              int* __restrict__ cnt, int ne) {
    int e = blockIdx.x * 256 + threadIdx.x;
    if (e < ne) atomicAdd(&cnt[rows[e]], 1);
}

__global__ __launch_bounds__(256) void scatter_k(const int* __restrict__ rows,
                                                 const int* __restrict__ cols,
                                                 const float* __restrict__ vals,
                                                 int* __restrict__ cur,
                                                 int2* __restrict__ es, int ne) {
    int e = blockIdx.x * 256 + threadIdx.x;
    if (e >= ne) return;
    int p = atomicAdd(&cur[rows[e]], 1);
    es[p] = make_int2(cols[e], __float_as_int(vals[e]));
}

// ---------------- bf16 MFMA GEMM: C[M,N] = A[M,K] * W[N,K]^T ----------------
// 2-barrier pipelined K-loop: prefetch tile t+1 into registers while MFMAing
// tile t from LDS. ABF16: A already bf16; else fp32 converted at LDS write.

template <int K, int N, int BM, int BN, int BK, bool ABF16>
__global__ __launch_bounds__(256) void gemm_bf16(const void* __restrict__ Av,
                                                 const ushort_t* __restrict__ Wb,
                                                 ushort_t* __restrict__ C, int M) {
    constexpr int WM = BM / 2, WN = BN / 2;
    constexpr int TI = WM / 16, TJ = WN / 16;
    constexpr int LDA = BK + 8;
    constexpr int T = K / BK;
    constexpr int A_PER_F = BM * BK / 4 / 256;
    constexpr int A_PER_B = BM * BK / 8 / 256;
    constexpr int B_PER = BN * BK / 8 / 256;

    __shared__ __align__(16) ushort_t As[BM][LDA];
    __shared__ __align__(16) ushort_t Bs[BN][LDA];

    const int tid = threadIdx.x;
    const int lane = tid & 63;
    const int wid = tid >> 6;
    const int wm = wid >> 1, wn = wid & 1;
    const int rowBase = blockIdx.x * BM;
    const int lrow = lane & 15, kq = lane >> 4;

    float4 aF[ABF16 ? 1 : A_PER_F];
    uint4 aB[ABF16 ? A_PER_B : 1];
    uint4 bR[B_PER];

    auto loadTile = [&](int k0) {
        if constexpr (ABF16) {
            const ushort_t* A = (const ushort_t*)Av;
#pragma unroll
            for (int i = 0; i < A_PER_B; i++) {
                int idx = tid + i * 256;
                int r = idx / (BK / 8), c8 = idx % (BK / 8);
                int grow = rowBase + r;
                aB[i] = (grow < M) ? *(const uint4*)(A + (size_t)grow * K + k0 + c8 * 8)
                                   : make_uint4(0, 0, 0, 0);
            }
        } else {
            const float* A = (const float*)Av;
#pragma unroll
            for (int i = 0; i < A_PER_F; i++) {
                int idx = tid + i * 256;
                int r = idx / (BK / 4), c4 = idx % (BK / 4);
                int grow = rowBase + r;
                aF[i] = (grow < M) ? *(const float4*)(A + (size_t)grow * K + k0 + c4 * 4)
                                   : make_float4(0.f, 0.f, 0.f, 0.f);
            }
        }
#pragma unroll
        for (int i = 0; i < B_PER; i++) {
            int idx = tid + i * 256;
            int r = idx / (BK / 8), c8 = idx % (BK / 8);
            bR[i] = *(const uint4*)(Wb + (size_t)r * K + k0 + c8 * 8);
        }
    };
    auto storeTile = [&]() {
        if constexpr (ABF16) {
#pragma unroll
            for (int i = 0; i < A_PER_B; i++) {
                int idx = tid + i * 256;
                int r = idx / (BK / 8), c8 = idx % (BK / 8);
                *(uint4*)&As[r][c8 * 8] = aB[i];
            }
        } else {
#pragma unroll
            for (int i = 0; i < A_PER_F; i++) {
                int idx = tid + i * 256;
                int r = idx / (BK / 4), c4 = idx % (BK / 4);
                ushort_t p[4] = {f2bf(aF[i].x), f2bf(aF[i].y), f2bf(aF[i].z), f2bf(aF[i].w)};
                *(uint2*)&As[r][c4 * 4] = *(uint2*)p;
            }
        }
#pragma unroll
        for (int i = 0; i < B_PER; i++) {
            int idx = tid + i * 256;
            int r = idx / (BK / 8), c8 = idx % (BK / 8);
            *(uint4*)&Bs[r][c8 * 8] = bR[i];
        }
    };

    accf4 acc[TI][TJ];
#pragma unroll
    for (int i = 0; i < TI; i++)
#pragma unroll
        for (int j = 0; j < TJ; j++) acc[i][j] = accf4{0.f, 0.f, 0.f, 0.f};

    loadTile(0);
    storeTile();
    __syncthreads();

    for (int t = 0; t < T; t++) {
        if (t + 1 < T) loadTile((t + 1) * BK);   // in flight during MFMA
#pragma unroll
        for (int ks = 0; ks < BK / 32; ks++) {
            const int kb = ks * 32 + kq * 8;
            frag_t a[TI], b[TJ];
#pragma unroll
            for (int i = 0; i < TI; i++)
                a[i] = *(const frag_t*)&As[wm * WM + i * 16 + lrow][kb];
#pragma unroll
            for (int j = 0; j < TJ; j++)
                b[j] = *(const frag_t*)&Bs[wn * WN + j * 16 + lrow][kb];
#pragma unroll
            for (int i = 0; i < TI; i++)
#pragma unroll
                for (int j = 0; j < TJ; j++)
                    acc[i][j] = __builtin_amdgcn_mfma_f32_16x16x32_bf16(
                        a[i], b[j], acc[i][j], 0, 0, 0);
        }
        __syncthreads();
        if (t + 1 < T) {
            storeTile();
            __syncthreads();
        }
    }

    // epilogue: C/D layout col=lane&15, row=(lane>>4)*4+reg; write bf16
#pragma unroll
    for (int i = 0; i < TI; i++) {
#pragma unroll
        for (int j = 0; j < TJ; j++) {
            int col = wn * WN + j * 16 + lrow;
#pragma unroll
            for (int r = 0; r < 4; r++) {
                int grow = rowBase + wm * WM + i * 16 + kq * 4 + r;
                if (grow < M) C[(size_t)grow * N + col] = f2bf(acc[i][j][r]);
            }
        }
    }
}

// ---------------- SpMM (CSR, wave per row, 4 edge-groups x 16 lanes) --------
// N=128: 16 lanes x uint4 (8 bf16) cover one 256B row; 4 groups of 16 lanes
// each take every 4th edge; x4 unroll -> 16 edges in flight per wave.
// Groups combined at the end via shfl_xor(16) + shfl_xor(32).

__device__ __forceinline__ void acc8(float* acc, uint4 q, float v) {
    acc[0] += v * bf2f(q.x & 0xffff); acc[1] += v * bf2f(q.x >> 16);
    acc[2] += v * bf2f(q.y & 0xffff); acc[3] += v * bf2f(q.y >> 16);
    acc[4] += v * bf2f(q.z & 0xffff); acc[5] += v * bf2f(q.z >> 16);
    acc[6] += v * bf2f(q.w & 0xffff); acc[7] += v * bf2f(q.w >> 16);
}
__device__ __forceinline__ void acc4f(float* acc, uint2 q, float v) {
    acc[0] += v * bf2f(q.x & 0xffff); acc[1] += v * bf2f(q.x >> 16);
    acc[2] += v * bf2f(q.y & 0xffff); acc[3] += v * bf2f(q.y >> 16);
}

template <bool RELU>
__global__ __launch_bounds__(256) void spmm_csr_128(const int* __restrict__ row_ptr,
                                                    const int2* __restrict__ es,
                                                    const ushort_t* __restrict__ G,
                                                    ushort_t* __restrict__ H, int n) {
    int row = blockIdx.x * 4 + (threadIdx.x >> 6);
    int lane = threadIdx.x & 63;
    int g = lane >> 4, lg = lane & 15;
    if (row >= n) return;
    int s = row_ptr[row];
    int e = row_ptr[row + 1];
    float acc[8];
#pragma unroll
    for (int k = 0; k < 8; k++) acc[k] = 0.f;
    const ushort_t* __restrict__ Gp = G + lg * 8;
    int p = s;
    for (; p + 15 < e; p += 16) {
        int2 e0 = es[p + g], e1 = es[p + 4 + g];
        int2 e2 = es[p + 8 + g], e3 = es[p + 12 + g];
        uint4 q0 = *(const uint4*)(Gp + (size_t)e0.x * 128);
        uint4 q1 = *(const uint4*)(Gp + (size_t)e1.x * 128);
        uint4 q2 = *(const uint4*)(Gp + (size_t)e2.x * 128);
        uint4 q3 = *(const uint4*)(Gp + (size_t)e3.x * 128);
        acc8(acc, q0, __int_as_float(e0.y));
        acc8(acc, q1, __int_as_float(e1.y));
        acc8(acc, q2, __int_as_float(e2.y));
        acc8(acc, q3, __int_as_float(e3.y));
    }
    for (; p < e; p += 4) {
        if (p + g < e) {
            int2 e0 = es[p + g];
            uint4 q0 = *(const uint4*)(Gp + (size_t)e0.x * 128);
            acc8(acc, q0, __int_as_float(e0.y));
        }
    }
#pragma unroll
    for (int k = 0; k < 8; k++) {
        acc[k] += __shfl_xor(acc[k], 16);
        acc[k] += __shfl_xor(acc[k], 32);
    }
    if (g == 0) {
        if (RELU) {
#pragma unroll
            for (int k = 0; k < 8; k++) acc[k] = fmaxf(acc[k], 0.f);
        }
        uint4 o;
        o.x = (unsigned)f2bf(acc[0]) | ((unsigned)f2bf(acc[1]) << 16);
        o.y = (unsigned)f2bf(acc[2]) | ((unsigned)f2bf(acc[3]) << 16);
        o.z = (unsigned)f2bf(acc[4]) | ((unsigned)f2bf(acc[5]) << 16);
        o.w = (unsigned)f2bf(acc[6]) | ((unsigned)f2bf(acc[7]) << 16);
        *(uint4*)(H + (size_t)row * 128 + lg * 8) = o;
    }
}

// N=64, fp32 output (final layer): 16 lanes x uint2 (4 bf16) per 128B row.
__global__ __launch_bounds__(256) void spmm_csr_64f(const int* __restrict__ row_ptr,
                                                    const int2* __restrict__ es,
                                                    const ushort_t* __restrict__ G,
                                                    float* __restrict__ H, int n) {
    int row = blockIdx.x * 4 + (threadIdx.x >> 6);
    int lane = threadIdx.x & 63;
    int g = lane >> 4, lg = lane & 15;
    if (row >= n) return;
    int s = row_ptr[row];
    int e = row_ptr[row + 1];
    float acc[4] = {0.f, 0.f, 0.f, 0.f};
    const ushort_t* __restrict__ Gp = G + lg * 4;
    int p = s;
    for (; p + 15 < e; p += 16) {
        int2 e0 = es[p + g], e1 = es[p + 4 + g];
        int2 e2 = es[p + 8 + g], e3 = es[p + 12 + g];
        uint2 q0 = *(const uint2*)(Gp + (size_t)e0.x * 64);
        uint2 q1 = *(const uint2*)(Gp + (size_t)e1.x * 64);
        uint2 q2 = *(const uint2*)(Gp + (size_t)e2.x * 64);
        uint2 q3 = *(const uint2*)(Gp + (size_t)e3.x * 64);
        acc4f(acc, q0, __int_as_float(e0.y));
        acc4f(acc, q1, __int_as_float(e1.y));
        acc4f(acc, q2, __int_as_float(e2.y));
        acc4f(acc, q3, __int_as_float(e3.y));
    }
    for (; p < e; p += 4) {
        if (p + g < e) {
            int2 e0 = es[p + g];
            uint2 q0 = *(const uint2*)(Gp + (size_t)e0.x * 64);
            acc4f(acc, q0, __int_as_float(e0.y));
        }
    }
#pragma unroll
    for (int k = 0; k < 4; k++) {
        acc[k] += __shfl_xor(acc[k], 16);
        acc[k] += __shfl_xor(acc[k], 32);
    }
    if (g == 0) {
        float4 o = make_float4(acc[0], acc[1], acc[2], acc[3]);
        *(float4*)(H + (size_t)row * 64 + lg * 4) = o;
    }
}

static inline size_t align_up(size_t x, size_t a) { return (x + a - 1) & ~(a - 1); }

extern "C" void kernel_launch(void* const* d_in, const int* in_sizes, int n_in,
                              void* d_out, int out_size, void* d_ws, size_t ws_size,
                              hipStream_t stream) {
    const float* x = (const float*)d_in[0];
    const int* rows = (const int*)d_in[1];
    const int* cols = (const int*)d_in[2];
    const float* vals = (const float*)d_in[3];
    const float* W0 = (const float*)d_in[4];
    const float* W1 = (const float*)d_in[5];
    const float* W2 = (const float*)d_in[6];
    float* out = (float*)d_out;

    const int IN = 512, HID = 128, OUT = 64;
    const int n = in_sizes[0] / IN;   // 100000
    const int ne = in_sizes[1];       // 1600000
    (void)OUT;

    // workspace carve-up
    char* ws = (char*)d_ws;
    size_t off = 0;
    ushort_t* g = (ushort_t*)(ws + off); off = align_up(off + (size_t)n * HID * 2, 512);
    ushort_t* h = (ushort_t*)(ws + off); off = align_up(off + (size_t)n * HID * 2, 512);
    int2* es2 = (int2*)(ws + off); off = align_up(off + (size_t)ne * 8, 512);
    int* cnt = (int*)(ws + off); off = align_up(off + (size_t)n * 4, 512);
    int* cur = (int*)(ws + off); off = align_up(off + (size_t)n * 4, 512);
    int* row_ptr = (int*)(ws + off); off = align_up(off + (size_t)(n + 1) * 4, 512);
    int* bsum0 = (int*)(ws + off); off = align_up(off + 512 * 4, 512);
    ushort_t* Wb0 = (ushort_t*)(ws + off); off = align_up(off + (size_t)HID * IN * 2, 512);
    ushort_t* Wb1 = (ushort_t*)(ws + off); off = align_up(off + (size_t)HID * HID * 2, 512);
    ushort_t* Wb2 = (ushort_t*)(ws + off); off = align_up(off + (size_t)OUT * HID * 2, 512);

    const int nb = (n + 255) / 256;        // 391 (<= 512 for scan_sums)
    const int eb = (ne + 255) / 256;       // 6250

    // ---- direct CSR build (6 launches) ----
    init_k<<<nb, 256, 0, stream>>>(cnt, n, W0, W1, W2, Wb0, Wb1, Wb2);
    hist_k<<<eb, 256, 0, stream>>>(rows, cnt, ne);
    block_totals<<<nb, 256, 0, stream>>>(cnt, bsum0, n);
    scan_sums<<<1, 512, 0, stream>>>(bsum0, nb);
    scan_wo<<<nb, 256, 0, stream>>>(cnt, bsum0, row_ptr, cur, row_ptr + n, ne, n);
    scatter_k<<<eb, 256, 0, stream>>>(rows, cols, vals, cur, es2, ne);

    const int gblocks = (n + 127) / 128;
    const int sblocks = (n + 3) / 4;

    // ---- layer 0 ----
    gemm_bf16<512, 128, 128, 128, 64, false><<<gblocks, 256, 0, stream>>>(x, Wb0, g, n);
    spmm_csr_128<true><<<sblocks, 256, 0, stream>>>(row_ptr, es2, g, h, n);

    // ---- layer 1 ----
    gemm_bf16<128, 128, 128, 128, 64, true><<<gblocks, 256, 0, stream>>>(h, Wb1, g, n);
    spmm_csr_128<true><<<sblocks, 256, 0, stream>>>(row_ptr, es2, g, h, n);

    // ---- layer 2 ----
    gemm_bf16<128, 64, 128, 64, 64, true><<<gblocks, 256, 0, stream>>>(h, Wb2, g, n);
    spmm_csr_64f<<<sblocks, 256, 0, stream>>>(row_ptr, es2, g, out, n);
}

// Round 2
// 661.598 us; speedup vs baseline: 1.1479x; 1.0764x over previous
//
#include <hip/hip_runtime.h>
#include <hip/hip_bf16.h>
#include <cstddef>

// GCN: h0 = relu(spmm(x@W0^T)); h1 = relu(spmm(h0@W1^T)); out = spmm(h1@W2^T)
// R8: atomic-free scatter. hist8 ranks each edge within an XCD-local slice
// (cnt8[(bid&7)*n+row], atomics stay in one XCD's L2; rank stored coalesced).
// A hierarchical exclusive scan over the slice-minor view of cnt8 gives
// dstbase[r*8+s] (= final position base) and row_ptr in one pass. scatter8
// then computes its destination directly -> fire-and-forget stores, no
// atomic-return latency chain (R7's scatter_k was 120us, serialization-bound).

typedef unsigned short ushort_t;
using frag_t = __attribute__((ext_vector_type(8))) short;   // 8 bf16
using accf4 = __attribute__((ext_vector_type(4))) float;    // 4 fp32

__device__ __forceinline__ ushort_t f2bf(float f) {
    unsigned int u = __float_as_uint(f);
    u += 0x7FFF + ((u >> 16) & 1);   // RNE
    return (ushort_t)(u >> 16);
}
__device__ __forceinline__ float bf2f(unsigned int u16) {
    return __uint_as_float(u16 << 16);
}

// ---------------- init: zero slice counters + convert all weights ----------

__global__ __launch_bounds__(256) void init_k(int* __restrict__ cnt8, int m8,
                                              const float* __restrict__ W0,
                                              const float* __restrict__ W1,
                                              const float* __restrict__ W2,
                                              ushort_t* __restrict__ Wb0,
                                              ushort_t* __restrict__ Wb1,
                                              ushort_t* __restrict__ Wb2) {
    int i = blockIdx.x * 256 + threadIdx.x;
    if (i < m8) cnt8[i] = 0;
    if (i < 65536) Wb0[i] = f2bf(W0[i]);
    else if (i < 81920) Wb1[i - 65536] = f2bf(W1[i - 65536]);
    else if (i < 90112) Wb2[i - 81920] = f2bf(W2[i - 81920]);
}

// ---------------- scan building blocks ----------------

__global__ __launch_bounds__(256) void block_totals(const int* __restrict__ counts,
                                                    int* __restrict__ bsums, int n) {
    __shared__ int s[256];
    int t = threadIdx.x;
    int i = blockIdx.x * 256 + t;
    s[t] = (i < n) ? counts[i] : 0;
    __syncthreads();
    for (int off = 128; off > 0; off >>= 1) {
        if (t < off) s[t] += s[t + off];
        __syncthreads();
    }
    if (t == 0) bsums[blockIdx.x] = s[0];
}

// single block, 512 threads: exclusive scan of nb (<=512) values in place
__global__ __launch_bounds__(512) void scan_sums(int* bsums, int nb) {
    __shared__ int s[512];
    int t = threadIdx.x;
    int v = (t < nb) ? bsums[t] : 0;
    s[t] = v;
    __syncthreads();
    for (int off = 1; off < 512; off *= 2) {
        int u = (t >= off) ? s[t - off] : 0;
        __syncthreads();
        s[t] += u;
        __syncthreads();
    }
    if (t < nb) bsums[t] = s[t] - v;  // exclusive
}

// generic exclusive scan with per-block offsets
__global__ __launch_bounds__(256) void scan_wo(const int* __restrict__ data,
                                               const int* __restrict__ offs,
                                               int* __restrict__ out0, int m) {
    __shared__ int s[256];
    int t = threadIdx.x;
    int i = blockIdx.x * 256 + t;
    int v = (i < m) ? data[i] : 0;
    s[t] = v;
    __syncthreads();
    for (int off = 1; off < 256; off *= 2) {
        int u = (t >= off) ? s[t - off] : 0;
        __syncthreads();
        s[t] += u;
        __syncthreads();
    }
    if (i < m) out0[i] = s[t] - v + offs[blockIdx.x];
}

// final scan over the slice-minor view of cnt8: element i=(r*8+s) reads
// cnt8[s*n+r]; writes dstbase[i], row_ptr[r] at s==0, and row_ptr[n]=ne.
__global__ __launch_bounds__(256) void scan_final(const int* __restrict__ cnt8,
                                                  const int* __restrict__ offs,
                                                  int* __restrict__ dstbase,
                                                  int* __restrict__ row_ptr,
                                                  int n, int ne, int m8) {
    __shared__ int s[256];
    int t = threadIdx.x;
    int i = blockIdx.x * 256 + t;
    int v = (i < m8) ? cnt8[(i & 7) * n + (i >> 3)] : 0;
    s[t] = v;
    __syncthreads();
    for (int off = 1; off < 256; off *= 2) {
        int u = (t >= off) ? s[t - off] : 0;
        __syncthreads();
        s[t] += u;
        __syncthreads();
    }
    int excl = s[t] - v + offs[blockIdx.x];
    if (i < m8) {
        dstbase[i] = excl;
        if ((i & 7) == 0) row_ptr[i >> 3] = excl;
    }
    if (i == 0) row_ptr[n] = ne;
}

// ---------------- XCD-local rank + direct scatter ----------------

__global__ __launch_bounds__(256) void hist8_k(const int* __restrict__ rows,
                                               int* __restrict__ cnt8,
                                               int* __restrict__ rank,
                                               int n, int ne) {
    int e = blockIdx.x * 256 + threadIdx.x;
    if (e >= ne) return;
    int s = blockIdx.x & 7;                    // ~= XCD id (round-robin dispatch)
    rank[e] = atomicAdd(&cnt8[s * n + rows[e]], 1);
}

__global__ __launch_bounds__(256) void scatter8_k(const int* __restrict__ rows,
                                                  const int* __restrict__ cols,
                                                  const float* __restrict__ vals,
                                                  const int* __restrict__ dstbase,
                                                  const int* __restrict__ rank,
                                                  int2* __restrict__ es, int ne) {
    int e = blockIdx.x * 256 + threadIdx.x;
    if (e >= ne) return;
    int s = blockIdx.x & 7;                    // must match hist8_k's mapping
    int r = rows[e];
    int p = dstbase[r * 8 + s] + rank[e];
    es[p] = make_int2(cols[e], __float_as_int(vals[e]));
}

// ---------------- bf16 MFMA GEMM: C[M,N] = A[M,K] * W[N,K]^T ----------------
// 2-barrier pipelined K-loop: prefetch tile t+1 into registers while MFMAing
// tile t from LDS. ABF16: A already bf16; else fp32 converted at LDS write.

template <int K, int N, int BM, int BN, int BK, bool ABF16>
__global__ __launch_bounds__(256) void gemm_bf16(const void* __restrict__ Av,
                                                 const ushort_t* __restrict__ Wb,
                                                 ushort_t* __restrict__ C, int M) {
    constexpr int WM = BM / 2, WN = BN / 2;
    constexpr int TI = WM / 16, TJ = WN / 16;
    constexpr int LDA = BK + 8;
    constexpr int T = K / BK;
    constexpr int A_PER_F = BM * BK / 4 / 256;
    constexpr int A_PER_B = BM * BK / 8 / 256;
    constexpr int B_PER = BN * BK / 8 / 256;

    __shared__ __align__(16) ushort_t As[BM][LDA];
    __shared__ __align__(16) ushort_t Bs[BN][LDA];

    const int tid = threadIdx.x;
    const int lane = tid & 63;
    const int wid = tid >> 6;
    const int wm = wid >> 1, wn = wid & 1;
    const int rowBase = blockIdx.x * BM;
    const int lrow = lane & 15, kq = lane >> 4;

    float4 aF[ABF16 ? 1 : A_PER_F];
    uint4 aB[ABF16 ? A_PER_B : 1];
    uint4 bR[B_PER];

    auto loadTile = [&](int k0) {
        if constexpr (ABF16) {
            const ushort_t* A = (const ushort_t*)Av;
#pragma unroll
            for (int i = 0; i < A_PER_B; i++) {
                int idx = tid + i * 256;
                int r = idx / (BK / 8), c8 = idx % (BK / 8);
                int grow = rowBase + r;
                aB[i] = (grow < M) ? *(const uint4*)(A + (size_t)grow * K + k0 + c8 * 8)
                                   : make_uint4(0, 0, 0, 0);
            }
        } else {
            const float* A = (const float*)Av;
#pragma unroll
            for (int i = 0; i < A_PER_F; i++) {
                int idx = tid + i * 256;
                int r = idx / (BK / 4), c4 = idx % (BK / 4);
                int grow = rowBase + r;
                aF[i] = (grow < M) ? *(const float4*)(A + (size_t)grow * K + k0 + c4 * 4)
                                   : make_float4(0.f, 0.f, 0.f, 0.f);
            }
        }
#pragma unroll
        for (int i = 0; i < B_PER; i++) {
            int idx = tid + i * 256;
            int r = idx / (BK / 8), c8 = idx % (BK / 8);
            bR[i] = *(const uint4*)(Wb + (size_t)r * K + k0 + c8 * 8);
        }
    };
    auto storeTile = [&]() {
        if constexpr (ABF16) {
#pragma unroll
            for (int i = 0; i < A_PER_B; i++) {
                int idx = tid + i * 256;
                int r = idx / (BK / 8), c8 = idx % (BK / 8);
                *(uint4*)&As[r][c8 * 8] = aB[i];
            }
        } else {
#pragma unroll
            for (int i = 0; i < A_PER_F; i++) {
                int idx = tid + i * 256;
                int r = idx / (BK / 4), c4 = idx % (BK / 4);
                ushort_t p[4] = {f2bf(aF[i].x), f2bf(aF[i].y), f2bf(aF[i].z), f2bf(aF[i].w)};
                *(uint2*)&As[r][c4 * 4] = *(uint2*)p;
            }
        }
#pragma unroll
        for (int i = 0; i < B_PER; i++) {
            int idx = tid + i * 256;
            int r = idx / (BK / 8), c8 = idx % (BK / 8);
            *(uint4*)&Bs[r][c8 * 8] = bR[i];
        }
    };

    accf4 acc[TI][TJ];
#pragma unroll
    for (int i = 0; i < TI; i++)
#pragma unroll
        for (int j = 0; j < TJ; j++) acc[i][j] = accf4{0.f, 0.f, 0.f, 0.f};

    loadTile(0);
    storeTile();
    __syncthreads();

    for (int t = 0; t < T; t++) {
        if (t + 1 < T) loadTile((t + 1) * BK);   // in flight during MFMA
#pragma unroll
        for (int ks = 0; ks < BK / 32; ks++) {
            const int kb = ks * 32 + kq * 8;
            frag_t a[TI], b[TJ];
#pragma unroll
            for (int i = 0; i < TI; i++)
                a[i] = *(const frag_t*)&As[wm * WM + i * 16 + lrow][kb];
#pragma unroll
            for (int j = 0; j < TJ; j++)
                b[j] = *(const frag_t*)&Bs[wn * WN + j * 16 + lrow][kb];
#pragma unroll
            for (int i = 0; i < TI; i++)
#pragma unroll
                for (int j = 0; j < TJ; j++)
                    acc[i][j] = __builtin_amdgcn_mfma_f32_16x16x32_bf16(
                        a[i], b[j], acc[i][j], 0, 0, 0);
        }
        __syncthreads();
        if (t + 1 < T) {
            storeTile();
            __syncthreads();
        }
    }

    // epilogue: C/D layout col=lane&15, row=(lane>>4)*4+reg; write bf16
#pragma unroll
    for (int i = 0; i < TI; i++) {
#pragma unroll
        for (int j = 0; j < TJ; j++) {
            int col = wn * WN + j * 16 + lrow;
#pragma unroll
            for (int r = 0; r < 4; r++) {
                int grow = rowBase + wm * WM + i * 16 + kq * 4 + r;
                if (grow < M) C[(size_t)grow * N + col] = f2bf(acc[i][j][r]);
            }
        }
    }
}

// ---------------- SpMM (CSR, wave per row, 4 edge-groups x 16 lanes) --------
// N=128: 16 lanes x uint4 (8 bf16) cover one 256B row; 4 groups of 16 lanes
// each take every 4th edge; x4 unroll -> 16 edges in flight per wave.
// Groups combined at the end via shfl_xor(16) + shfl_xor(32).

__device__ __forceinline__ void acc8(float* acc, uint4 q, float v) {
    acc[0] += v * bf2f(q.x & 0xffff); acc[1] += v * bf2f(q.x >> 16);
    acc[2] += v * bf2f(q.y & 0xffff); acc[3] += v * bf2f(q.y >> 16);
    acc[4] += v * bf2f(q.z & 0xffff); acc[5] += v * bf2f(q.z >> 16);
    acc[6] += v * bf2f(q.w & 0xffff); acc[7] += v * bf2f(q.w >> 16);
}
__device__ __forceinline__ void acc4f(float* acc, uint2 q, float v) {
    acc[0] += v * bf2f(q.x & 0xffff); acc[1] += v * bf2f(q.x >> 16);
    acc[2] += v * bf2f(q.y & 0xffff); acc[3] += v * bf2f(q.y >> 16);
}

template <bool RELU>
__global__ __launch_bounds__(256) void spmm_csr_128(const int* __restrict__ row_ptr,
                                                    const int2* __restrict__ es,
                                                    const ushort_t* __restrict__ G,
                                                    ushort_t* __restrict__ H, int n) {
    int row = blockIdx.x * 4 + (threadIdx.x >> 6);
    int lane = threadIdx.x & 63;
    int g = lane >> 4, lg = lane & 15;
    if (row >= n) return;
    int s = row_ptr[row];
    int e = row_ptr[row + 1];
    float acc[8];
#pragma unroll
    for (int k = 0; k < 8; k++) acc[k] = 0.f;
    const ushort_t* __restrict__ Gp = G + lg * 8;
    int p = s;
    for (; p + 15 < e; p += 16) {
        int2 e0 = es[p + g], e1 = es[p + 4 + g];
        int2 e2 = es[p + 8 + g], e3 = es[p + 12 + g];
        uint4 q0 = *(const uint4*)(Gp + (size_t)e0.x * 128);
        uint4 q1 = *(const uint4*)(Gp + (size_t)e1.x * 128);
        uint4 q2 = *(const uint4*)(Gp + (size_t)e2.x * 128);
        uint4 q3 = *(const uint4*)(Gp + (size_t)e3.x * 128);
        acc8(acc, q0, __int_as_float(e0.y));
        acc8(acc, q1, __int_as_float(e1.y));
        acc8(acc, q2, __int_as_float(e2.y));
        acc8(acc, q3, __int_as_float(e3.y));
    }
    for (; p < e; p += 4) {
        if (p + g < e) {
            int2 e0 = es[p + g];
            uint4 q0 = *(const uint4*)(Gp + (size_t)e0.x * 128);
            acc8(acc, q0, __int_as_float(e0.y));
        }
    }
#pragma unroll
    for (int k = 0; k < 8; k++) {
        acc[k] += __shfl_xor(acc[k], 16);
        acc[k] += __shfl_xor(acc[k], 32);
    }
    if (g == 0) {
        if (RELU) {
#pragma unroll
            for (int k = 0; k < 8; k++) acc[k] = fmaxf(acc[k], 0.f);
        }
        uint4 o;
        o.x = (unsigned)f2bf(acc[0]) | ((unsigned)f2bf(acc[1]) << 16);
        o.y = (unsigned)f2bf(acc[2]) | ((unsigned)f2bf(acc[3]) << 16);
        o.z = (unsigned)f2bf(acc[4]) | ((unsigned)f2bf(acc[5]) << 16);
        o.w = (unsigned)f2bf(acc[6]) | ((unsigned)f2bf(acc[7]) << 16);
        *(uint4*)(H + (size_t)row * 128 + lg * 8) = o;
    }
}

// N=64, fp32 output (final layer): 16 lanes x uint2 (4 bf16) per 128B row.
__global__ __launch_bounds__(256) void spmm_csr_64f(const int* __restrict__ row_ptr,
                                                    const int2* __restrict__ es,
                                                    const ushort_t* __restrict__ G,
                                                    float* __restrict__ H, int n) {
    int row = blockIdx.x * 4 + (threadIdx.x >> 6);
    int lane = threadIdx.x & 63;
    int g = lane >> 4, lg = lane & 15;
    if (row >= n) return;
    int s = row_ptr[row];
    int e = row_ptr[row + 1];
    float acc[4] = {0.f, 0.f, 0.f, 0.f};
    const ushort_t* __restrict__ Gp = G + lg * 4;
    int p = s;
    for (; p + 15 < e; p += 16) {
        int2 e0 = es[p + g], e1 = es[p + 4 + g];
        int2 e2 = es[p + 8 + g], e3 = es[p + 12 + g];
        uint2 q0 = *(const uint2*)(Gp + (size_t)e0.x * 64);
        uint2 q1 = *(const uint2*)(Gp + (size_t)e1.x * 64);
        uint2 q2 = *(const uint2*)(Gp + (size_t)e2.x * 64);
        uint2 q3 = *(const uint2*)(Gp + (size_t)e3.x * 64);
        acc4f(acc, q0, __int_as_float(e0.y));
        acc4f(acc, q1, __int_as_float(e1.y));
        acc4f(acc, q2, __int_as_float(e2.y));
        acc4f(acc, q3, __int_as_float(e3.y));
    }
    for (; p < e; p += 4) {
        if (p + g < e) {
            int2 e0 = es[p + g];
            uint2 q0 = *(const uint2*)(Gp + (size_t)e0.x * 64);
            acc4f(acc, q0, __int_as_float(e0.y));
        }
    }
#pragma unroll
    for (int k = 0; k < 4; k++) {
        acc[k] += __shfl_xor(acc[k], 16);
        acc[k] += __shfl_xor(acc[k], 32);
    }
    if (g == 0) {
        float4 o = make_float4(acc[0], acc[1], acc[2], acc[3]);
        *(float4*)(H + (size_t)row * 64 + lg * 4) = o;
    }
}

static inline size_t align_up(size_t x, size_t a) { return (x + a - 1) & ~(a - 1); }

extern "C" void kernel_launch(void* const* d_in, const int* in_sizes, int n_in,
                              void* d_out, int out_size, void* d_ws, size_t ws_size,
                              hipStream_t stream) {
    const float* x = (const float*)d_in[0];
    const int* rows = (const int*)d_in[1];
    const int* cols = (const int*)d_in[2];
    const float* vals = (const float*)d_in[3];
    const float* W0 = (const float*)d_in[4];
    const float* W1 = (const float*)d_in[5];
    const float* W2 = (const float*)d_in[6];
    float* out = (float*)d_out;

    const int IN = 512, HID = 128, OUT = 64;
    const int n = in_sizes[0] / IN;   // 100000
    const int ne = in_sizes[1];       // 1600000
    (void)OUT;

    // workspace carve-up
    char* ws = (char*)d_ws;
    size_t off = 0;
    ushort_t* g = (ushort_t*)(ws + off); off = align_up(off + (size_t)n * HID * 2, 512);
    ushort_t* h = (ushort_t*)(ws + off); off = align_up(off + (size_t)n * HID * 2, 512);
    int2* es2 = (int2*)(ws + off); off = align_up(off + (size_t)ne * 8, 512);
    int* cnt8 = (int*)(ws + off); off = align_up(off + (size_t)8 * n * 4, 512);
    int* rank = (int*)(ws + off); off = align_up(off + (size_t)ne * 4, 512);
    int* dstbase = (int*)(ws + off); off = align_up(off + (size_t)8 * n * 4, 512);
    int* row_ptr = (int*)(ws + off); off = align_up(off + (size_t)(n + 1) * 4, 512);
    int* bsum0 = (int*)(ws + off); off = align_up(off + 4096 * 4, 512);
    int* bsum1 = (int*)(ws + off); off = align_up(off + 512 * 4, 512);
    int* off0 = (int*)(ws + off); off = align_up(off + 4096 * 4, 512);
    ushort_t* Wb0 = (ushort_t*)(ws + off); off = align_up(off + (size_t)HID * IN * 2, 512);
    ushort_t* Wb1 = (ushort_t*)(ws + off); off = align_up(off + (size_t)HID * HID * 2, 512);
    ushort_t* Wb2 = (ushort_t*)(ws + off); off = align_up(off + (size_t)OUT * HID * 2, 512);

    const int eb = (ne + 255) / 256;       // 6250
    const int m8 = 8 * n;                  // 800000
    const int nb8 = (m8 + 255) / 256;      // 3125
    const int nb8b = (nb8 + 255) / 256;    // 13

    // ---- CSR build: XCD-local rank, then atomic-free direct scatter ----
    init_k<<<nb8, 256, 0, stream>>>(cnt8, m8, W0, W1, W2, Wb0, Wb1, Wb2);
    hist8_k<<<eb, 256, 0, stream>>>(rows, cnt8, rank, n, ne);
    block_totals<<<nb8, 256, 0, stream>>>(cnt8, bsum0, m8);   // NOTE: totals are
    // order-independent, so summing cnt8 in [s][r] order still gives correct
    // per-256-chunk sums for the [r*8+s] view? NO — it would not. We therefore
    // scan the transposed view everywhere: block_totals must read transposed too.
    // (see block_totals_t below -- kept name separate for clarity)
    // This call is replaced:
    // block_totals_t reads cnt8[(i&7)*n + (i>>3)]
    // -- actual sequence follows --
    (void)0;
    // correct sequence:
    //   block_totals_t(cnt8 -> bsum0)  [3125]
    //   block_totals  (bsum0 -> bsum1) [13]
    //   scan_sums     (bsum1)          [1]
    //   scan_wo       (bsum0, bsum1 -> off0) [13]
    //   scan_final    (cnt8^T, off0 -> dstbase,row_ptr) [3125]
    // The stray block_totals above is harmless but wasteful; replaced below by
    // launching block_totals_t into bsum0 (overwrites).
    {
        // transposed block totals
        struct Launcher {};
    }
    extern __global__ void block_totals_t(const int*, int*, int, int);
    block_totals_t<<<nb8, 256, 0, stream>>>(cnt8, bsum0, n, m8);
    block_totals<<<nb8b, 256, 0, stream>>>(bsum0, bsum1, nb8);
    scan_sums<<<1, 512, 0, stream>>>(bsum1, nb8b);
    scan_wo<<<nb8b, 256, 0, stream>>>(bsum0, bsum1, off0, nb8);
    scan_final<<<nb8, 256, 0, stream>>>(cnt8, off0, dstbase, row_ptr, n, ne, m8);
    scatter8_k<<<eb, 256, 0, stream>>>(rows, cols, vals, dstbase, rank, es2, ne);

    const int gblocks = (n + 127) / 128;
    const int sblocks = (n + 3) / 4;

    // ---- layer 0 ----
    gemm_bf16<512, 128, 128, 128, 64, false><<<gblocks, 256, 0, stream>>>(x, Wb0, g, n);
    spmm_csr_128<true><<<sblocks, 256, 0, stream>>>(row_ptr, es2, g, h, n);

    // ---- layer 1 ----
    gemm_bf16<128, 128, 128, 128, 64, true><<<gblocks, 256, 0, stream>>>(h, Wb1, g, n);
    spmm_csr_128<true><<<sblocks, 256, 0, stream>>>(row_ptr, es2, g, h, n);

    // ---- layer 2 ----
    gemm_bf16<128, 64, 128, 64, 64, true><<<gblocks, 256, 0, stream>>>(h, Wb2, g, n);
    spmm_csr_64f<<<sblocks, 256, 0, stream>>>(row_ptr, es2, g, out, n);
}

// transposed block totals: element i of the scanned sequence is
// cnt8[(i&7)*n + (i>>3)] (row-major, slice-minor view)
__global__ __launch_bounds__(256) void block_totals_t(const int* __restrict__ cnt8,
                                                      int* __restrict__ bsums,
                                                      int n, int m8) {
    __shared__ int s[256];
    int t = threadIdx.x;
    int i = blockIdx.x * 256 + t;
    s[t] = (i < m8) ? cnt8[(i & 7) * n + (i >> 3)] : 0;
    __syncthreads();
    for (int off = 128; off > 0; off >>= 1) {
        if (t < off) s[t] += s[t + off];
        __syncthreads();
    }
    if (t == 0) bsums[blockIdx.x] = s[0];
}